// Round 8
// baseline (144.923 us; speedup 1.0000x reference)
//
#include <hip/hip_runtime.h>
#include <stdint.h>

#define BN            16384
#define PHASE_PTS     4096
#define NPHASE        4
#define BLOCK_THREADS 1024
#define NWAVES        (BLOCK_THREADS / 64)
#define KOUT          16

typedef float v2f __attribute__((ext_vector_type(2)));
union F4 { float4 f4; v2f p[2]; float f[4]; };

// sortable key of float bits (ascending uint == ascending float)
__device__ __forceinline__ unsigned key_u(unsigned u) {
    return u ^ ((unsigned)((int)u >> 31) | 0x80000000u);
}
// whole-wave shift-right by 1; lane 0 receives `oldv` (VALU DPP, no LDS pipe)
__device__ __forceinline__ unsigned wshr1(unsigned v, unsigned oldv) {
    return (unsigned)__builtin_amdgcn_update_dpp((int)oldv, (int)v, 0x138 /*WAVE_SHR:1*/,
                                                 0xF, 0xF, false);
}
#define RL16(T) __uint_as_float((unsigned)__builtin_amdgcn_readlane(__float_as_int(T), 16))

// Minimal sorted insert: stale candidates fall into the sorted junk zone (lanes 17+).
#define DRAIN(m, p, T, J)                                                           \
    while (m) {                                                                     \
        const int b_ = (int)__builtin_ctzll(m);                                     \
        m &= m - 1;                                                                 \
        const float pc_ = __uint_as_float(                                          \
            (unsigned)__builtin_amdgcn_readlane(__float_as_int(p), b_));            \
        const unsigned jc_ = (unsigned)(jbase + b_);                                \
        const float Tup_ =                                                          \
            __uint_as_float(wshr1(__float_as_uint(T), 0xFF800000u /*-inf*/));       \
        const unsigned Jup_ = wshr1((J), 0u);                                       \
        const bool lt_ = (pc_ < Tup_);                                              \
        const float Tn_ = lt_ ? Tup_ : pc_;                                         \
        const unsigned Jn_ = lt_ ? Jup_ : jc_;                                      \
        const bool sel_ = (pc_ < (T));                                              \
        (T) = sel_ ? Tn_ : (T);                                                     \
        (J) = sel_ ? Jn_ : (J);                                                     \
    }

// d2 = ((2*dot + nsq_q) + nsq_j) for both queries, bitwise == reference chain.
#define EVALC(c, d2)                                                                \
    asm("v_pk_mul_f32 %0, %1, %2 op_sel:[0,0] op_sel_hi:[0,1]"                      \
        : "=v"(d2) : "v"((c).p[0]), "v"(c0A));                                      \
    asm("v_pk_fma_f32 %0, %1, %2, %0 op_sel:[1,0,0] op_sel_hi:[1,1,1]"              \
        : "+v"(d2) : "v"((c).p[0]), "v"(c1A));                                      \
    asm("v_pk_fma_f32 %0, %1, %2, %0 op_sel:[0,0,0] op_sel_hi:[0,1,1]"              \
        : "+v"(d2) : "v"((c).p[1]), "v"(c2A));                                      \
    asm("v_pk_add_f32 %0, %0, %1" : "+v"(d2) : "v"(nsq01));                         \
    asm("v_pk_add_f32 %0, %0, %1 op_sel:[0,1] op_sel_hi:[1,1]"                      \
        : "+v"(d2) : "v"((c).p[1]));

#define PROC(tile, c)                                                               \
    do {                                                                            \
        v2f d2;                                                                     \
        EVALC(c, d2)                                                                \
        uint64_t m0 = __ballot(d2[0] < fF0);                                        \
        uint64_t m1 = __ballot(d2[1] < fF1);                                        \
        if (m0 | m1) {                                                              \
            const int jbase = pbase + (tile) * 64;                                  \
            const float p0 = d2[0], p1 = d2[1];                                     \
            DRAIN(m0, p0, T0, J0)                                                   \
            DRAIN(m1, p1, T1, J1)                                                   \
            fF0 = RL16(T0);                                                         \
            fF1 = RL16(T1);                                                         \
        }                                                                           \
    } while (0)

// Group of 4 tiles: first NL from LDS, rest straight from the L2-resident table.
// Loads hoisted ahead of evals -> 4 outstanding loads/wave on two parallel pipes.
#define GROUP4(tb, NL)                                                              \
    do {                                                                            \
        F4 cg[4];                                                                   \
        _Pragma("unroll") for (int u = 0; u < 4; ++u) {                             \
            if (u < (NL)) cg[u].f4 = buf[((tb) + u) * 64 + lane];                   \
            else          cg[u].f4 = tab[pbase + ((tb) + u) * 64 + lane];           \
        }                                                                           \
        _Pragma("unroll") for (int u = 0; u < 4; ++u) PROC((tb) + u, cg[u]);        \
    } while (0)

#define STAGE_PHASE(ph)                                                             \
    do {                                                                            \
        _Pragma("unroll")                                                           \
        for (int kk = 0; kk < PHASE_PTS / BLOCK_THREADS; ++kk) {                    \
            const int pl = tid + kk * BLOCK_THREADS;                                \
            buf[pl] = tab[(ph) * PHASE_PTS + pl];                                   \
        }                                                                           \
    } while (0)

// Wave-parallel exact sort of 64 (p, j=lane) pairs via rank computation (R7).
__device__ __forceinline__ void presort64(float p, int lane, double* sw,
                                          float& T, unsigned& J) {
    const double dm = (double)key_u(__float_as_uint(p)) * 64.0 + (double)lane;
    sw[lane] = dm;
    unsigned rank = 0;
    const char* sb = (const char*)sw;
    unsigned off = (unsigned)lane * 8u;
#pragma unroll 7
    for (int s = 1; s < 64; ++s) {
        off = (off + 8u) & 511u;  // rotate: mild conflicts, negligible
        const double dn = *(const double*)(sb + off);
        rank += (dn < dm) ? 1u : 0u;
    }
    sw[rank] = __longlong_as_double(
        (long long)(((unsigned long long)(unsigned)lane << 32) | __float_as_uint(p)));
    const unsigned long long v = (unsigned long long)__double_as_longlong(sw[lane]);
    T = __uint_as_float((unsigned)(v & 0xFFFFFFFFull));
    J = (unsigned)(v >> 32);
}

// Precompute kernel: float4 (x, y, z, -sq) table in workspace (L2-resident, 256 KB).
__global__ __launch_bounds__(256) void build_tab(const float* __restrict__ x,
                                                 float4* __restrict__ tab) {
    const int i = blockIdx.x * 256 + threadIdx.x;
    const float gx = x[3 * i], gy = x[3 * i + 1], gz = x[3 * i + 2];
    const float nsq = -__fadd_rn(__fadd_rn(__fmul_rn(gx, gx), __fmul_rn(gy, gy)),
                                 __fmul_rn(gz, gz));
    tab[i] = make_float4(gx, gy, gz, nsq);
}

__global__ __launch_bounds__(BLOCK_THREADS) void knn_far_kernel(
    const float4* __restrict__ tab, float* __restrict__ out_d, float* __restrict__ out_i) {
    extern __shared__ char smem[];  // 64KB tile buf + 512B/wave sort scratch
    float4* buf = (float4*)smem;
    double* sw  = (double*)(smem + PHASE_PTS * sizeof(float4)) + (threadIdx.x >> 6) * 64;

    const int tid  = threadIdx.x;
    const int lane = tid & 63;
    const int wid  = tid >> 6;
    const int q0   = (blockIdx.x * NWAVES + wid) * 2;  // 2 queries/wave
    const int q1   = q0 + 1;

    // Query data from the table (identical values/rounding as reference).
    const float4 qa = tab[q0], qb = tab[q1];
    const v2f nsq01 = {qa.w, qb.w};
    // Pre-doubled packed query coeffs (x2 exact; pk chain == 2*dot of ref, bitwise).
    const v2f c0A = {2.0f * qa.x, 2.0f * qb.x};
    const v2f c1A = {2.0f * qa.y, 2.0f * qb.y};
    const v2f c2A = {2.0f * qa.z, 2.0f * qb.z};

    float    T0, T1;
    unsigned J0, J1;
    float    fF0, fF1;

    // ---- phase 0 ----
    {
        STAGE_PHASE(0);
        __syncthreads();
        const int pbase = 0;
        {   // group 0: tiles 0-2 LDS, 3 global; tile 0 seeds lists via presort
            F4 cg[4];
#pragma unroll
            for (int u = 0; u < 4; ++u) {
                if (u < 3) cg[u].f4 = buf[u * 64 + lane];
                else       cg[u].f4 = tab[u * 64 + lane];
            }
            {
                v2f d2;
                EVALC(cg[0], d2)
                presort64(d2[0], lane, sw, T0, J0);
                presort64(d2[1], lane, sw, T1, J1);
                fF0 = RL16(T0);
                fF1 = RL16(T1);
            }
            PROC(1, cg[1]);
            PROC(2, cg[2]);
            PROC(3, cg[3]);
        }
        for (int g = 1; g < PHASE_PTS / 256; ++g) GROUP4(g * 4, (g & 1) ? 2 : 3);
    }

    // ---- phases 1..3 ----
    for (int ph = 1; ph < NPHASE; ++ph) {
        __syncthreads();
        STAGE_PHASE(ph);
        __syncthreads();
        const int pbase = ph * PHASE_PTS;
        for (int g = 0; g < PHASE_PTS / 256; ++g) GROUP4(g * 4, (g & 1) ? 2 : 3);
    }

    // ranks 1..16 (rank 0 = overall farthest is dropped by the reference slicing)
    if (lane >= 1 && lane <= KOUT) {
        const int r = lane - 1;
        out_d[q0 * KOUT + r] = T0;
        out_i[q0 * KOUT + r] = (float)J0;
        out_d[q1 * KOUT + r] = T1;
        out_i[q1 * KOUT + r] = (float)J1;
    }
}

extern "C" void kernel_launch(void* const* d_in, const int* in_sizes, int n_in,
                              void* d_out, int out_size, void* d_ws, size_t ws_size,
                              hipStream_t stream) {
    const float* x = (const float*)d_in[0];
    float4* tab = (float4*)d_ws;               // 16384 * 16 B = 256 KB workspace
    float* out_d = (float*)d_out;              // 8*2048*16 dists
    float* out_i = out_d + (size_t)BN * KOUT;  // 8*2048*16 indices (as float)

    hipLaunchKernelGGL(build_tab, dim3(BN / 256), dim3(256), 0, stream, x, tab);

    const int queries_per_block = 2 * NWAVES;
    const size_t shmem = PHASE_PTS * sizeof(float4) + NWAVES * 64 * sizeof(double);
    hipLaunchKernelGGL(knn_far_kernel, dim3(BN / queries_per_block), dim3(BLOCK_THREADS),
                       shmem, stream, tab, out_d, out_i);
}

// Round 9
// 100.413 us; speedup vs baseline: 1.4433x; 1.4433x over previous
//
#include <hip/hip_runtime.h>
#include <stdint.h>

#define BN       16384
#define NTILES   256     // BN/64
#define NB       64      // norm buckets
#define KOUT     16
#define MARGIN   0.01f   // certified slack >> max fp32 eval error (~4e-5)

typedef float v2f __attribute__((ext_vector_type(2)));
union F4 { float4 f4; v2f p[2]; float f[4]; };

// ---- workspace layout (bytes) ----
#define WS_TAB    0                        // float4[BN]   262144
#define WS_IDX    (WS_TAB + BN * 16)       // u32[BN]       65536
#define WS_TMAX   (WS_IDX + BN * 4)        // u32[NTILES]    1024
#define WS_BND    (WS_TMAX + NTILES * 4)   // float2[NTILES] 2048
#define WS_CNT    (WS_BND + NTILES * 8)    // u32[NB]
#define WS_BASE   (WS_CNT + NB * 4)        // u32[NB]
#define WS_CUR    (WS_BASE + NB * 4)       // u32[NB]

// sortable key of float bits (ascending uint == ascending float)
__device__ __forceinline__ unsigned key_u(unsigned u) {
    return u ^ ((unsigned)((int)u >> 31) | 0x80000000u);
}
__device__ __forceinline__ unsigned wshr1(unsigned v, unsigned oldv) {
    return (unsigned)__builtin_amdgcn_update_dpp((int)oldv, (int)v, 0x138 /*WAVE_SHR:1*/,
                                                 0xF, 0xF, false);
}
#define RL16(T) __uint_as_float((unsigned)__builtin_amdgcn_readlane(__float_as_int(T), 16))

// exact np-order squared norm: (x^2 + y^2) + z^2
__device__ __forceinline__ float sq_of(float gx, float gy, float gz) {
    return __fadd_rn(__fadd_rn(__fmul_rn(gx, gx), __fmul_rn(gy, gy)), __fmul_rn(gz, gz));
}
__device__ __forceinline__ int bucket_of(float sq) {
    const float rho = __fsqrt_rn(sq);
    int b = (int)(64.0f * (1.0f - rho * 0.2f));  // edges rho_b = 5*(1-b/64)
    return (b < 0) ? 0 : ((b > 63) ? 63 : b);
}

// Lexicographic (pair asc, idx asc) sorted insert -> scan-order independent.
#define DRAIN(m, p, jvec, T, J)                                                     \
    while (m) {                                                                     \
        const int b_ = (int)__builtin_ctzll(m);                                     \
        m &= m - 1;                                                                 \
        const float pc_ = __uint_as_float(                                          \
            (unsigned)__builtin_amdgcn_readlane(__float_as_int(p), b_));            \
        const unsigned jc_ = (unsigned)__builtin_amdgcn_readlane((int)(jvec), b_);  \
        const float Tup_ =                                                          \
            __uint_as_float(wshr1(__float_as_uint(T), 0xFF800000u /*-inf*/));       \
        const unsigned Jup_ = wshr1((J), 0u);                                       \
        const bool lt_ = (pc_ < Tup_) || ((pc_ == Tup_) && (jc_ < Jup_));           \
        const float Tn_ = lt_ ? Tup_ : pc_;                                         \
        const unsigned Jn_ = lt_ ? Jup_ : jc_;                                      \
        const bool sel_ = (pc_ < (T)) || ((pc_ == (T)) && (jc_ < (J)));             \
        (T) = sel_ ? Tn_ : (T);                                                     \
        (J) = sel_ ? Jn_ : (J);                                                     \
    }

// d2 = ((2*dot + nsq_q) + nsq_j) packed for 2 queries, bitwise == reference chain.
#define EVALC(c, d2)                                                                \
    asm("v_pk_mul_f32 %0, %1, %2 op_sel:[0,0] op_sel_hi:[0,1]"                      \
        : "=v"(d2) : "v"((c).p[0]), "v"(c0A));                                      \
    asm("v_pk_fma_f32 %0, %1, %2, %0 op_sel:[1,0,0] op_sel_hi:[1,1,1]"              \
        : "+v"(d2) : "v"((c).p[0]), "v"(c1A));                                      \
    asm("v_pk_fma_f32 %0, %1, %2, %0 op_sel:[0,0,0] op_sel_hi:[0,1,1]"              \
        : "+v"(d2) : "v"((c).p[1]), "v"(c2A));                                      \
    asm("v_pk_add_f32 %0, %0, %1" : "+v"(d2) : "v"(nsq01));                         \
    asm("v_pk_add_f32 %0, %0, %1 op_sel:[0,1] op_sel_hi:[1,1]"                      \
        : "+v"(d2) : "v"((c).p[1]));

#define TILE_AT(t)                                                                  \
    F4 c; c.f4 = tab[(t) * 64 + lane];                                              \
    const unsigned jvec = idxarr[(t) * 64 + lane];                                  \
    v2f d2; EVALC(c, d2)

#define PROCESS_LOADED()                                                            \
    do {                                                                            \
        uint64_t m0 = __ballot(d2[0] <= fF0);                                       \
        uint64_t m1 = __ballot(d2[1] <= fF1);                                       \
        if (m0 | m1) {                                                              \
            const float p0 = d2[0], p1 = d2[1];                                     \
            DRAIN(m0, p0, jvec, T0, J0)                                             \
            DRAIN(m1, p1, jvec, T1, J1)                                             \
            fF0 = RL16(T0); thr0 = __fsub_rn(-fF0, MARGIN);                         \
            fF1 = RL16(T1); thr1 = __fsub_rn(-fF1, MARGIN);                         \
        }                                                                           \
    } while (0)

// Wave-parallel exact sort of 64 (p, j) pairs by (p asc, j asc).
// Ordering scalar key(p)*16384 + j is exact in double (<= 2^46).
__device__ __forceinline__ void presort64(float p, unsigned j, int lane, double* sw,
                                          float& T, unsigned& J) {
    const double dm = (double)key_u(__float_as_uint(p)) * 16384.0 + (double)j;
    sw[lane] = dm;
    unsigned rank = 0;
    const char* sb = (const char*)sw;
    unsigned off = (unsigned)lane * 8u;
#pragma unroll 7
    for (int s = 1; s < 64; ++s) {
        off = (off + 8u) & 511u;
        const double dn = *(const double*)(sb + off);
        rank += (dn < dm) ? 1u : 0u;
    }
    sw[rank] = __longlong_as_double(
        (long long)(((unsigned long long)j << 32) | __float_as_uint(p)));
    const unsigned long long v = (unsigned long long)__double_as_longlong(sw[lane]);
    T = __uint_as_float((unsigned)(v & 0xFFFFFFFFull));
    J = (unsigned)(v >> 32);
}

// ---- prep kernels ----
__global__ __launch_bounds__(256) void k_zero(unsigned* cnt, unsigned* tmax) {
    const int t = threadIdx.x;
    if (t < NB) cnt[t] = 0u;
    tmax[t] = 0u;
}

__global__ __launch_bounds__(256) void k_count(const float* __restrict__ x,
                                               unsigned* __restrict__ cnt) {
    __shared__ unsigned h[NB];
    const int tid = threadIdx.x;
    if (tid < NB) h[tid] = 0u;
    __syncthreads();
    const int i = blockIdx.x * 256 + tid;
    const float sq = sq_of(x[3 * i], x[3 * i + 1], x[3 * i + 2]);
    atomicAdd(&h[bucket_of(sq)], 1u);
    __syncthreads();
    if (tid < NB && h[tid]) atomicAdd(&cnt[tid], h[tid]);
}

__global__ __launch_bounds__(64) void k_prefix(const unsigned* __restrict__ cnt,
                                               unsigned* __restrict__ base,
                                               unsigned* __restrict__ cur) {
    const int t = threadIdx.x;
    unsigned s = 0;
    for (int b = 0; b < t; ++b) s += cnt[b];
    base[t] = s;
    cur[t] = s;
}

__global__ __launch_bounds__(256) void k_scatter(const float* __restrict__ x,
                                                 unsigned* __restrict__ cur,
                                                 float4* __restrict__ tab,
                                                 unsigned* __restrict__ idxarr,
                                                 unsigned* __restrict__ tmax) {
    __shared__ unsigned h[NB], gb[NB];
    const int tid = threadIdx.x;
    if (tid < NB) h[tid] = 0u;
    __syncthreads();
    const int i = blockIdx.x * 256 + tid;
    const float gx = x[3 * i], gy = x[3 * i + 1], gz = x[3 * i + 2];
    const float sq = sq_of(gx, gy, gz);
    const int b = bucket_of(sq);
    const unsigned loff = atomicAdd(&h[b], 1u);
    __syncthreads();
    if (tid < NB && h[tid]) gb[tid] = atomicAdd(&cur[tid], h[tid]);
    __syncthreads();
    const unsigned pos = gb[b] + loff;
    tab[pos] = make_float4(gx, gy, gz, -sq);
    idxarr[pos] = (unsigned)i;
    atomicMax(&tmax[pos >> 6], __float_as_uint(sq));  // sq>0: float bits monotone
}

__global__ __launch_bounds__(256) void k_bounds(const unsigned* __restrict__ tmax,
                                                float2* __restrict__ bnd) {
    __shared__ unsigned m[NTILES];
    const int t = threadIdx.x;
    m[t] = tmax[t];
    __syncthreads();
    unsigned M = 0;
    for (int s = t; s < NTILES; ++s) M = (m[s] > M) ? m[s] : M;  // suffix max
    const float B = __uint_as_float(M);
    const float sqB_up = __uint_as_float(__float_as_uint(__fsqrt_rn(B)) + 2u);
    bnd[t] = make_float2(B, sqB_up);
}

// ---- main kernel: 4 waves/block, 2 queries/wave, prefix scan w/ certified break ----
__global__ __launch_bounds__(256) void knn_far_kernel(
    const float* __restrict__ x, const float4* __restrict__ tab,
    const unsigned* __restrict__ idxarr, const float2* __restrict__ bnd,
    float* __restrict__ out_d, float* __restrict__ out_i) {
    __shared__ double swall[4 * 64];
    const int tid  = threadIdx.x;
    const int lane = tid & 63;
    const int wid  = tid >> 6;
    double* sw = swall + wid * 64;
    const int q0 = (blockIdx.x * 4 + wid) * 2;
    const int q1 = q0 + 1;

    const float a0 = x[3 * q0], a1 = x[3 * q0 + 1], a2 = x[3 * q0 + 2];
    const float b0 = x[3 * q1], b1 = x[3 * q1 + 1], b2 = x[3 * q1 + 2];
    const float sq0 = sq_of(a0, a1, a2), sq1 = sq_of(b0, b1, b2);
    const v2f nsq01 = {-sq0, -sq1};
    const v2f c0A = {2.0f * a0, 2.0f * b0};
    const v2f c1A = {2.0f * a1, 2.0f * b1};
    const v2f c2A = {2.0f * a2, 2.0f * b2};
    // upper-bounded 2*|q| for the certificate
    const float twor0 = 2.0f * __uint_as_float(__float_as_uint(__fsqrt_rn(sq0)) + 2u);
    const float twor1 = 2.0f * __uint_as_float(__float_as_uint(__fsqrt_rn(sq1)) + 2u);

    float T0, T1; unsigned J0, J1;
    float fF0, fF1, thr0, thr1;

    {   // tile 0: seed via wave-parallel presort (no insert flood)
        TILE_AT(0)
        presort64(d2[0], jvec, lane, sw, T0, J0);
        presort64(d2[1], jvec, lane, sw, T1, J1);
        fF0 = RL16(T0); thr0 = __fsub_rn(-fF0, MARGIN);
        fF1 = RL16(T1); thr1 = __fsub_rn(-fF1, MARGIN);
    }
#pragma unroll
    for (int t = 1; t < 4; ++t) {  // rest of the seed region (top-256 norms)
        TILE_AT(t)
        PROCESS_LOADED();
    }
    for (int t = 4; t < NTILES; ++t) {
        const float2 bd = bnd[t];  // B = max sq_p over tiles >= t ; bd.y = sqrt(B) up
        const float u0 = __builtin_fmaf(twor0, bd.y, __fadd_rn(sq0, bd.x));
        const float u1 = __builtin_fmaf(twor1, bd.y, __fadd_rn(sq1, bd.x));
        if (u0 < thr0 && u1 < thr1) break;  // certified: no future point can matter
        TILE_AT(t)
        PROCESS_LOADED();
    }

    if (lane >= 1 && lane <= KOUT) {  // ranks 1..16 (rank 0 dropped by reference)
        const int r = lane - 1;
        out_d[q0 * KOUT + r] = T0;
        out_i[q0 * KOUT + r] = (float)J0;
        out_d[q1 * KOUT + r] = T1;
        out_i[q1 * KOUT + r] = (float)J1;
    }
}

extern "C" void kernel_launch(void* const* d_in, const int* in_sizes, int n_in,
                              void* d_out, int out_size, void* d_ws, size_t ws_size,
                              hipStream_t stream) {
    const float* x = (const float*)d_in[0];
    char* ws = (char*)d_ws;
    float4*   tab    = (float4*)(ws + WS_TAB);
    unsigned* idxarr = (unsigned*)(ws + WS_IDX);
    unsigned* tmax   = (unsigned*)(ws + WS_TMAX);
    float2*   bnd    = (float2*)(ws + WS_BND);
    unsigned* cnt    = (unsigned*)(ws + WS_CNT);
    unsigned* base   = (unsigned*)(ws + WS_BASE);
    unsigned* cur    = (unsigned*)(ws + WS_CUR);
    float* out_d = (float*)d_out;
    float* out_i = out_d + (size_t)BN * KOUT;

    hipLaunchKernelGGL(k_zero,    dim3(1),        dim3(256), 0, stream, cnt, tmax);
    hipLaunchKernelGGL(k_count,   dim3(BN / 256), dim3(256), 0, stream, x, cnt);
    hipLaunchKernelGGL(k_prefix,  dim3(1),        dim3(64),  0, stream, cnt, base, cur);
    hipLaunchKernelGGL(k_scatter, dim3(BN / 256), dim3(256), 0, stream, x, cur, tab, idxarr, tmax);
    hipLaunchKernelGGL(k_bounds,  dim3(1),        dim3(256), 0, stream, tmax, bnd);
    hipLaunchKernelGGL(knn_far_kernel, dim3(BN / 8), dim3(256), 0, stream,
                       x, tab, idxarr, bnd, out_d, out_i);
}

// Round 10
// 91.316 us; speedup vs baseline: 1.5870x; 1.0996x over previous
//
#include <hip/hip_runtime.h>
#include <stdint.h>

#define BN       16384
#define NTILES   256     // BN/64
#define NB       64      // norm buckets
#define KOUT     16
#define MARGIN   0.01f   // certified slack >> max fp32 eval error (~4e-5)
#define PPT      16      // points/thread in prep (16384/1024)

typedef float v2f __attribute__((ext_vector_type(2)));
union F4 { float4 f4; v2f p[2]; float f[4]; };

// ---- workspace layout (bytes) ----
#define WS_TAB    0                        // float4[BN]   262144
#define WS_IDX    (WS_TAB + BN * 16)       // u32[BN]       65536
#define WS_BND    (WS_IDX + BN * 4)        // float2[NTILES] 2048

// sortable key of float bits (ascending uint == ascending float)
__device__ __forceinline__ unsigned key_u(unsigned u) {
    return u ^ ((unsigned)((int)u >> 31) | 0x80000000u);
}
__device__ __forceinline__ unsigned wshr1(unsigned v, unsigned oldv) {
    return (unsigned)__builtin_amdgcn_update_dpp((int)oldv, (int)v, 0x138 /*WAVE_SHR:1*/,
                                                 0xF, 0xF, false);
}
#define RL16(T) __uint_as_float((unsigned)__builtin_amdgcn_readlane(__float_as_int(T), 16))

// exact np-order squared norm: (x^2 + y^2) + z^2
__device__ __forceinline__ float sq_of(float gx, float gy, float gz) {
    return __fadd_rn(__fadd_rn(__fmul_rn(gx, gx), __fmul_rn(gy, gy)), __fmul_rn(gz, gz));
}
__device__ __forceinline__ int bucket_of(float sq) {
    const float rho = __fsqrt_rn(sq);
    int b = (int)(64.0f * (1.0f - rho * 0.2f));  // edges rho_b = 5*(1-b/64)
    return (b < 0) ? 0 : ((b > 63) ? 63 : b);
}

// Lexicographic (pair asc, idx asc) sorted insert -> scan-order independent.
#define DRAIN(m, p, jvec, T, J)                                                     \
    while (m) {                                                                     \
        const int b_ = (int)__builtin_ctzll(m);                                     \
        m &= m - 1;                                                                 \
        const float pc_ = __uint_as_float(                                          \
            (unsigned)__builtin_amdgcn_readlane(__float_as_int(p), b_));            \
        const unsigned jc_ = (unsigned)__builtin_amdgcn_readlane((int)(jvec), b_);  \
        const float Tup_ =                                                          \
            __uint_as_float(wshr1(__float_as_uint(T), 0xFF800000u /*-inf*/));       \
        const unsigned Jup_ = wshr1((J), 0u);                                       \
        const bool lt_ = (pc_ < Tup_) || ((pc_ == Tup_) && (jc_ < Jup_));           \
        const float Tn_ = lt_ ? Tup_ : pc_;                                         \
        const unsigned Jn_ = lt_ ? Jup_ : jc_;                                      \
        const bool sel_ = (pc_ < (T)) || ((pc_ == (T)) && (jc_ < (J)));             \
        (T) = sel_ ? Tn_ : (T);                                                     \
        (J) = sel_ ? Jn_ : (J);                                                     \
    }

// d2 = ((2*dot + nsq_q) + nsq_j) packed for 2 queries, bitwise == reference chain.
#define EVALC(c, d2)                                                                \
    asm("v_pk_mul_f32 %0, %1, %2 op_sel:[0,0] op_sel_hi:[0,1]"                      \
        : "=v"(d2) : "v"((c).p[0]), "v"(c0A));                                      \
    asm("v_pk_fma_f32 %0, %1, %2, %0 op_sel:[1,0,0] op_sel_hi:[1,1,1]"              \
        : "+v"(d2) : "v"((c).p[0]), "v"(c1A));                                      \
    asm("v_pk_fma_f32 %0, %1, %2, %0 op_sel:[0,0,0] op_sel_hi:[0,1,1]"              \
        : "+v"(d2) : "v"((c).p[1]), "v"(c2A));                                      \
    asm("v_pk_add_f32 %0, %0, %1" : "+v"(d2) : "v"(nsq01));                         \
    asm("v_pk_add_f32 %0, %0, %1 op_sel:[0,1] op_sel_hi:[1,1]"                      \
        : "+v"(d2) : "v"((c).p[1]));

#define TILE_AT(t)                                                                  \
    F4 c; c.f4 = tab[(t) * 64 + lane];                                              \
    const unsigned jvec = idxarr[(t) * 64 + lane];                                  \
    v2f d2; EVALC(c, d2)

#define PROCESS_LOADED()                                                            \
    do {                                                                            \
        uint64_t m0 = __ballot(d2[0] <= fF0);                                       \
        uint64_t m1 = __ballot(d2[1] <= fF1);                                       \
        if (m0 | m1) {                                                              \
            const float p0 = d2[0], p1 = d2[1];                                     \
            DRAIN(m0, p0, jvec, T0, J0)                                             \
            DRAIN(m1, p1, jvec, T1, J1)                                             \
            fF0 = RL16(T0); thr0 = __fsub_rn(-fF0, MARGIN);                         \
            fF1 = RL16(T1); thr1 = __fsub_rn(-fF1, MARGIN);                         \
        }                                                                           \
    } while (0)

// Wave-parallel exact sort of 64 (p, j) pairs by (p asc, j asc).
// Ordering scalar key(p)*16384 + j is exact in double (<= 2^46).
__device__ __forceinline__ void presort64(float p, unsigned j, int lane, double* sw,
                                          float& T, unsigned& J) {
    const double dm = (double)key_u(__float_as_uint(p)) * 16384.0 + (double)j;
    sw[lane] = dm;
    unsigned rank = 0;
    const char* sb = (const char*)sw;
    unsigned off = (unsigned)lane * 8u;
#pragma unroll 7
    for (int s = 1; s < 64; ++s) {
        off = (off + 8u) & 511u;
        const double dn = *(const double*)(sb + off);
        rank += (dn < dm) ? 1u : 0u;
    }
    sw[rank] = __longlong_as_double(
        (long long)(((unsigned long long)j << 32) | __float_as_uint(p)));
    const unsigned long long v = (unsigned long long)__double_as_longlong(sw[lane]);
    T = __uint_as_float((unsigned)(v & 0xFFFFFFFFull));
    J = (unsigned)(v >> 32);
}

// ---- fused single-block prep: histogram -> prefix -> scatter -> bounds ----
__global__ __launch_bounds__(1024) void k_prep(const float* __restrict__ x,
                                               float4* __restrict__ tab,
                                               unsigned* __restrict__ idxarr,
                                               float2* __restrict__ bnd) {
    __shared__ unsigned hist[NB];
    __shared__ unsigned curs[NB];
    __shared__ unsigned tmaxs[NTILES];
    const int tid = threadIdx.x;
    if (tid < NB) hist[tid] = 0u;
    if (tid < NTILES) tmaxs[tid] = 0u;
    __syncthreads();

    float px[PPT], py[PPT], pz[PPT], psq[PPT];
    int pb[PPT];
#pragma unroll
    for (int k = 0; k < PPT; ++k) {
        const int i = tid + k * 1024;  // coalesced across lanes
        const float gx = x[3 * i], gy = x[3 * i + 1], gz = x[3 * i + 2];
        const float sq = sq_of(gx, gy, gz);
        px[k] = gx; py[k] = gy; pz[k] = gz; psq[k] = sq;
        pb[k] = bucket_of(sq);
        atomicAdd(&hist[pb[k]], 1u);
    }
    __syncthreads();
    if (tid == 0) {  // 64-bucket exclusive prefix, trivial serial
        unsigned s = 0;
        for (int b = 0; b < NB; ++b) { curs[b] = s; s += hist[b]; }
    }
    __syncthreads();
#pragma unroll
    for (int k = 0; k < PPT; ++k) {
        const int i = tid + k * 1024;
        const unsigned pos = atomicAdd(&curs[pb[k]], 1u);
        tab[pos] = make_float4(px[k], py[k], pz[k], -psq[k]);
        idxarr[pos] = (unsigned)i;
        atomicMax(&tmaxs[pos >> 6], __float_as_uint(psq[k]));  // sq>0: bits monotone
    }
    __syncthreads();
    // suffix max over tiles, log steps
    for (int s = 1; s < NTILES; s <<= 1) {
        unsigned v = 0;
        if (tid < NTILES) {
            v = tmaxs[tid];
            if (tid + s < NTILES) { const unsigned w = tmaxs[tid + s]; v = (w > v) ? w : v; }
        }
        __syncthreads();
        if (tid < NTILES) tmaxs[tid] = v;
        __syncthreads();
    }
    if (tid < NTILES) {
        const float B = __uint_as_float(tmaxs[tid]);
        const float sqB_up = __uint_as_float(__float_as_uint(__fsqrt_rn(B)) + 2u);
        bnd[tid] = make_float2(B, sqB_up);
    }
}

// ---- main kernel: 4 waves/block, 2 queries/wave, prefix scan w/ certified break ----
__global__ __launch_bounds__(256) void knn_far_kernel(
    const float* __restrict__ x, const float4* __restrict__ tab,
    const unsigned* __restrict__ idxarr, const float2* __restrict__ bnd,
    float* __restrict__ out_d, float* __restrict__ out_i) {
    __shared__ double swall[4 * 64];
    const int tid  = threadIdx.x;
    const int lane = tid & 63;
    const int wid  = tid >> 6;
    double* sw = swall + wid * 64;
    const int q0 = (blockIdx.x * 4 + wid) * 2;
    const int q1 = q0 + 1;

    const float a0 = x[3 * q0], a1 = x[3 * q0 + 1], a2 = x[3 * q0 + 2];
    const float b0 = x[3 * q1], b1 = x[3 * q1 + 1], b2 = x[3 * q1 + 2];
    const float sq0 = sq_of(a0, a1, a2), sq1 = sq_of(b0, b1, b2);
    const v2f nsq01 = {-sq0, -sq1};
    const v2f c0A = {2.0f * a0, 2.0f * b0};
    const v2f c1A = {2.0f * a1, 2.0f * b1};
    const v2f c2A = {2.0f * a2, 2.0f * b2};
    // upper-bounded 2*|q| for the certificate
    const float twor0 = 2.0f * __uint_as_float(__float_as_uint(__fsqrt_rn(sq0)) + 2u);
    const float twor1 = 2.0f * __uint_as_float(__float_as_uint(__fsqrt_rn(sq1)) + 2u);

    float T0, T1; unsigned J0, J1;
    float fF0, fF1, thr0, thr1;

    {   // tile 0: seed via wave-parallel presort (no insert flood)
        TILE_AT(0)
        presort64(d2[0], jvec, lane, sw, T0, J0);
        presort64(d2[1], jvec, lane, sw, T1, J1);
        fF0 = RL16(T0); thr0 = __fsub_rn(-fF0, MARGIN);
        fF1 = RL16(T1); thr1 = __fsub_rn(-fF1, MARGIN);
    }
#pragma unroll
    for (int t = 1; t < 4; ++t) {  // rest of the seed region (top-256 norms)
        TILE_AT(t)
        PROCESS_LOADED();
    }
    for (int t = 4; t < NTILES; ++t) {
        const float2 bd = bnd[t];  // B = max sq_p over tiles >= t ; bd.y = sqrt(B) up
        const float u0 = __builtin_fmaf(twor0, bd.y, __fadd_rn(sq0, bd.x));
        const float u1 = __builtin_fmaf(twor1, bd.y, __fadd_rn(sq1, bd.x));
        if (u0 < thr0 && u1 < thr1) break;  // certified: no future point can matter
        TILE_AT(t)
        PROCESS_LOADED();
    }

    if (lane >= 1 && lane <= KOUT) {  // ranks 1..16 (rank 0 dropped by reference)
        const int r = lane - 1;
        out_d[q0 * KOUT + r] = T0;
        out_i[q0 * KOUT + r] = (float)J0;
        out_d[q1 * KOUT + r] = T1;
        out_i[q1 * KOUT + r] = (float)J1;
    }
}

extern "C" void kernel_launch(void* const* d_in, const int* in_sizes, int n_in,
                              void* d_out, int out_size, void* d_ws, size_t ws_size,
                              hipStream_t stream) {
    const float* x = (const float*)d_in[0];
    char* ws = (char*)d_ws;
    float4*   tab    = (float4*)(ws + WS_TAB);
    unsigned* idxarr = (unsigned*)(ws + WS_IDX);
    float2*   bnd    = (float2*)(ws + WS_BND);
    float* out_d = (float*)d_out;
    float* out_i = out_d + (size_t)BN * KOUT;

    hipLaunchKernelGGL(k_prep, dim3(1), dim3(1024), 0, stream, x, tab, idxarr, bnd);
    hipLaunchKernelGGL(knn_far_kernel, dim3(BN / 8), dim3(256), 0, stream,
                       x, tab, idxarr, bnd, out_d, out_i);
}

// Round 11
// 90.981 us; speedup vs baseline: 1.5929x; 1.0037x over previous
//
#include <hip/hip_runtime.h>
#include <stdint.h>

#define BN       16384
#define NTILES   256     // BN/64
#define NB       64      // norm buckets
#define NW       16      // waves in prep block
#define KOUT     16
#define MARGIN   0.01f   // certified slack >> max fp32 eval error (~4e-5)
#define PPT      16      // points/thread in prep (16384/1024)

typedef float v2f __attribute__((ext_vector_type(2)));
union F4 { float4 f4; v2f p[2]; float f[4]; };

// ---- workspace layout (bytes) ----
#define WS_TAB    0                        // float4[BN]   262144
#define WS_IDX    (WS_TAB + BN * 16)       // u32[BN]       65536
#define WS_BND    (WS_IDX + BN * 4)        // float2[NTILES] 2048

// sortable key of float bits (ascending uint == ascending float)
__device__ __forceinline__ unsigned key_u(unsigned u) {
    return u ^ ((unsigned)((int)u >> 31) | 0x80000000u);
}
__device__ __forceinline__ unsigned wshr1(unsigned v, unsigned oldv) {
    return (unsigned)__builtin_amdgcn_update_dpp((int)oldv, (int)v, 0x138 /*WAVE_SHR:1*/,
                                                 0xF, 0xF, false);
}
#define RL16(T) __uint_as_float((unsigned)__builtin_amdgcn_readlane(__float_as_int(T), 16))

// exact np-order squared norm: (x^2 + y^2) + z^2
__device__ __forceinline__ float sq_of(float gx, float gy, float gz) {
    return __fadd_rn(__fadd_rn(__fmul_rn(gx, gx), __fmul_rn(gy, gy)), __fmul_rn(gz, gz));
}
__device__ __forceinline__ int bucket_of(float sq) {
    const float rho = __fsqrt_rn(sq);
    int b = (int)(64.0f * (1.0f - rho * 0.2f));  // edges rho_b = 5*(1-b/64)
    return (b < 0) ? 0 : ((b > 63) ? 63 : b);
}

// Lexicographic (pair asc, idx asc) sorted insert -> scan-order independent.
#define DRAIN(m, p, jvec, T, J)                                                     \
    while (m) {                                                                     \
        const int b_ = (int)__builtin_ctzll(m);                                     \
        m &= m - 1;                                                                 \
        const float pc_ = __uint_as_float(                                          \
            (unsigned)__builtin_amdgcn_readlane(__float_as_int(p), b_));            \
        const unsigned jc_ = (unsigned)__builtin_amdgcn_readlane((int)(jvec), b_);  \
        const float Tup_ =                                                          \
            __uint_as_float(wshr1(__float_as_uint(T), 0xFF800000u /*-inf*/));       \
        const unsigned Jup_ = wshr1((J), 0u);                                       \
        const bool lt_ = (pc_ < Tup_) || ((pc_ == Tup_) && (jc_ < Jup_));           \
        const float Tn_ = lt_ ? Tup_ : pc_;                                         \
        const unsigned Jn_ = lt_ ? Jup_ : jc_;                                      \
        const bool sel_ = (pc_ < (T)) || ((pc_ == (T)) && (jc_ < (J)));             \
        (T) = sel_ ? Tn_ : (T);                                                     \
        (J) = sel_ ? Jn_ : (J);                                                     \
    }

// d2 = ((2*dot + nsq_q) + nsq_j) packed for 2 queries, bitwise == reference chain.
#define EVALC(c, d2)                                                                \
    asm("v_pk_mul_f32 %0, %1, %2 op_sel:[0,0] op_sel_hi:[0,1]"                      \
        : "=v"(d2) : "v"((c).p[0]), "v"(c0A));                                      \
    asm("v_pk_fma_f32 %0, %1, %2, %0 op_sel:[1,0,0] op_sel_hi:[1,1,1]"              \
        : "+v"(d2) : "v"((c).p[0]), "v"(c1A));                                      \
    asm("v_pk_fma_f32 %0, %1, %2, %0 op_sel:[0,0,0] op_sel_hi:[0,1,1]"              \
        : "+v"(d2) : "v"((c).p[1]), "v"(c2A));                                      \
    asm("v_pk_add_f32 %0, %0, %1" : "+v"(d2) : "v"(nsq01));                         \
    asm("v_pk_add_f32 %0, %0, %1 op_sel:[0,1] op_sel_hi:[1,1]"                      \
        : "+v"(d2) : "v"((c).p[1]));

#define TILE_AT(t)                                                                  \
    F4 c; c.f4 = tab[(t) * 64 + lane];                                              \
    const unsigned jvec = idxarr[(t) * 64 + lane];                                  \
    v2f d2; EVALC(c, d2)

#define PROCESS_LOADED()                                                            \
    do {                                                                            \
        uint64_t m0 = __ballot(d2[0] <= fF0);                                       \
        uint64_t m1 = __ballot(d2[1] <= fF1);                                       \
        if (m0 | m1) {                                                              \
            const float p0 = d2[0], p1 = d2[1];                                     \
            DRAIN(m0, p0, jvec, T0, J0)                                             \
            DRAIN(m1, p1, jvec, T1, J1)                                             \
            fF0 = RL16(T0); thr0 = __fsub_rn(-fF0, MARGIN);                         \
            fF1 = RL16(T1); thr1 = __fsub_rn(-fF1, MARGIN);                         \
        }                                                                           \
    } while (0)

// Wave-parallel exact sort of 64 (p, j) pairs by (p asc, j asc).
// Ordering scalar key(p)*16384 + j is exact in double (<= 2^46).
__device__ __forceinline__ void presort64(float p, unsigned j, int lane, double* sw,
                                          float& T, unsigned& J) {
    const double dm = (double)key_u(__float_as_uint(p)) * 16384.0 + (double)j;
    sw[lane] = dm;
    unsigned rank = 0;
    const char* sb = (const char*)sw;
    unsigned off = (unsigned)lane * 8u;
#pragma unroll 7
    for (int s = 1; s < 64; ++s) {
        off = (off + 8u) & 511u;
        const double dn = *(const double*)(sb + off);
        rank += (dn < dm) ? 1u : 0u;
    }
    sw[rank] = __longlong_as_double(
        (long long)(((unsigned long long)j << 32) | __float_as_uint(p)));
    const unsigned long long v = (unsigned long long)__double_as_longlong(sw[lane]);
    T = __uint_as_float((unsigned)(v & 0xFFFFFFFFull));
    J = (unsigned)(v >> 32);
}

// ---- fused single-block prep with per-wave histograms (no cross-wave LDS
// atomic serialization): hist -> prefix -> scatter -> bounds ----
__global__ __launch_bounds__(1024) void k_prep(const float* __restrict__ x,
                                               float4* __restrict__ tab,
                                               unsigned* __restrict__ idxarr,
                                               float2* __restrict__ bnd) {
    __shared__ unsigned cnt[NW * 65];   // per-wave hist/cursors, +1 pad rotates banks
    __shared__ unsigned base[NB];
    __shared__ unsigned tmaxs[NTILES];
    const int tid  = threadIdx.x;
    const int wid  = tid >> 6;
    for (int i = tid; i < NW * 65; i += 1024) cnt[i] = 0u;
    if (tid < NTILES) tmaxs[tid] = 0u;
    __syncthreads();

    float px[PPT], py[PPT], pz[PPT], psq[PPT];
    int pb[PPT];
#pragma unroll
    for (int k = 0; k < PPT; ++k) {
        const int i = tid + k * 1024;  // coalesced across lanes
        const float gx = x[3 * i], gy = x[3 * i + 1], gz = x[3 * i + 2];
        const float sq = sq_of(gx, gy, gz);
        px[k] = gx; py[k] = gy; pz[k] = gz; psq[k] = sq;
        pb[k] = bucket_of(sq);
        atomicAdd(&cnt[wid * 65 + pb[k]], 1u);  // wave-private: ~12-way max conflict
    }
    __syncthreads();
    if (tid < NB) {  // bucket totals
        unsigned s = 0;
#pragma unroll
        for (int w = 0; w < NW; ++w) s += cnt[w * 65 + tid];
        base[tid] = s;
    }
    __syncthreads();
    if (tid == 0) {  // exclusive prefix over 64 buckets
        unsigned s = 0;
        for (int b = 0; b < NB; ++b) { const unsigned t = base[b]; base[b] = s; s += t; }
    }
    __syncthreads();
    if (tid < NB) {  // convert per-wave counts -> per-wave cursor bases, in place
        unsigned s = base[tid];
#pragma unroll
        for (int w = 0; w < NW; ++w) {
            const unsigned t = cnt[w * 65 + tid];
            cnt[w * 65 + tid] = s;
            s += t;
        }
    }
    __syncthreads();
#pragma unroll
    for (int k = 0; k < PPT; ++k) {
        const int i = tid + k * 1024;
        const unsigned pos = atomicAdd(&cnt[wid * 65 + pb[k]], 1u);  // wave-private
        tab[pos] = make_float4(px[k], py[k], pz[k], -psq[k]);
        idxarr[pos] = (unsigned)i;
        atomicMax(&tmaxs[pos >> 6], __float_as_uint(psq[k]));  // sq>0: bits monotone
    }
    __syncthreads();
    // suffix max over tiles, log steps
    for (int s = 1; s < NTILES; s <<= 1) {
        unsigned v = 0;
        if (tid < NTILES) {
            v = tmaxs[tid];
            if (tid + s < NTILES) { const unsigned w = tmaxs[tid + s]; v = (w > v) ? w : v; }
        }
        __syncthreads();
        if (tid < NTILES) tmaxs[tid] = v;
        __syncthreads();
    }
    if (tid < NTILES) {
        const float B = __uint_as_float(tmaxs[tid]);
        const float sqB_up = __uint_as_float(__float_as_uint(__fsqrt_rn(B)) + 2u);
        bnd[tid] = make_float2(B, sqB_up);
    }
}

// ---- main kernel: 4 waves/block, 2 queries/wave, prefix scan w/ certified break ----
__global__ __launch_bounds__(256) void knn_far_kernel(
    const float* __restrict__ x, const float4* __restrict__ tab,
    const unsigned* __restrict__ idxarr, const float2* __restrict__ bnd,
    float* __restrict__ out_d, float* __restrict__ out_i) {
    __shared__ double swall[4 * 64];
    const int tid  = threadIdx.x;
    const int lane = tid & 63;
    const int wid  = tid >> 6;
    double* sw = swall + wid * 64;
    const int q0 = (blockIdx.x * 4 + wid) * 2;
    const int q1 = q0 + 1;

    const float a0 = x[3 * q0], a1 = x[3 * q0 + 1], a2 = x[3 * q0 + 2];
    const float b0 = x[3 * q1], b1 = x[3 * q1 + 1], b2 = x[3 * q1 + 2];
    const float sq0 = sq_of(a0, a1, a2), sq1 = sq_of(b0, b1, b2);
    const v2f nsq01 = {-sq0, -sq1};
    const v2f c0A = {2.0f * a0, 2.0f * b0};
    const v2f c1A = {2.0f * a1, 2.0f * b1};
    const v2f c2A = {2.0f * a2, 2.0f * b2};
    // upper-bounded 2*|q| for the certificate
    const float twor0 = 2.0f * __uint_as_float(__float_as_uint(__fsqrt_rn(sq0)) + 2u);
    const float twor1 = 2.0f * __uint_as_float(__float_as_uint(__fsqrt_rn(sq1)) + 2u);

    float T0, T1; unsigned J0, J1;
    float fF0, fF1, thr0, thr1;

    {   // tile 0: seed via wave-parallel presort (no insert flood)
        TILE_AT(0)
        presort64(d2[0], jvec, lane, sw, T0, J0);
        presort64(d2[1], jvec, lane, sw, T1, J1);
        fF0 = RL16(T0); thr0 = __fsub_rn(-fF0, MARGIN);
        fF1 = RL16(T1); thr1 = __fsub_rn(-fF1, MARGIN);
    }
#pragma unroll
    for (int t = 1; t < 4; ++t) {  // rest of the seed region (top-256 norms)
        TILE_AT(t)
        PROCESS_LOADED();
    }
    for (int t = 4; t < NTILES; ++t) {
        const float2 bd = bnd[t];  // B = max sq_p over tiles >= t ; bd.y = sqrt(B) up
        const float u0 = __builtin_fmaf(twor0, bd.y, __fadd_rn(sq0, bd.x));
        const float u1 = __builtin_fmaf(twor1, bd.y, __fadd_rn(sq1, bd.x));
        if (u0 < thr0 && u1 < thr1) break;  // certified: no future point can matter
        TILE_AT(t)
        PROCESS_LOADED();
    }

    if (lane >= 1 && lane <= KOUT) {  // ranks 1..16 (rank 0 dropped by reference)
        const int r = lane - 1;
        out_d[q0 * KOUT + r] = T0;
        out_i[q0 * KOUT + r] = (float)J0;
        out_d[q1 * KOUT + r] = T1;
        out_i[q1 * KOUT + r] = (float)J1;
    }
}

extern "C" void kernel_launch(void* const* d_in, const int* in_sizes, int n_in,
                              void* d_out, int out_size, void* d_ws, size_t ws_size,
                              hipStream_t stream) {
    const float* x = (const float*)d_in[0];
    char* ws = (char*)d_ws;
    float4*   tab    = (float4*)(ws + WS_TAB);
    unsigned* idxarr = (unsigned*)(ws + WS_IDX);
    float2*   bnd    = (float2*)(ws + WS_BND);
    float* out_d = (float*)d_out;
    float* out_i = out_d + (size_t)BN * KOUT;

    hipLaunchKernelGGL(k_prep, dim3(1), dim3(1024), 0, stream, x, tab, idxarr, bnd);
    hipLaunchKernelGGL(knn_far_kernel, dim3(BN / 8), dim3(256), 0, stream,
                       x, tab, idxarr, bnd, out_d, out_i);
}